// Round 1
// 195.812 us; speedup vs baseline: 1.0201x; 1.0201x over previous
//
#include <hip/hip_runtime.h>
#include <cstddef>

#define N_ENT   2000
#define GAT_EMB 64
#define HIDDEN  256
#define BATCH   8
#define ALPHA   0.2f

typedef _Float16 half4 __attribute__((ext_vector_type(4)));
typedef int iv4 __attribute__((ext_vector_type(4)));
typedef float fv4 __attribute__((ext_vector_type(4)));

// Non-temporal 16B loads: NT bit -> no/evict-first allocation, avoiding
// dirty-victim writeback churn from the harness's 512 MB poison fill + 128 MB
// adj restore that precede every timed launch (prev session: -10.7 us measured).
__device__ __forceinline__ iv4 nt_load4i(const int* p) {
    return __builtin_nontemporal_load((const iv4*)p);
}
__device__ __forceinline__ fv4 nt_load4f(const float* p) {
    return __builtin_nontemporal_load((const fv4*)p);
}

// ws byte layout:
//   [0,      8192)   s2f  float[2048]      (pad zeroed by k_prep)
//   [8192,  12288)   hx   _Float16[2048]   (pad zeroed)
//   [12288, 16384)   hy   _Float16[2048]
//   [16384, 20480)   hz   _Float16[2048]
//   [20480, 28672)   s1f  float[2048]
//   [28672, 124672)  x16  _Float16[6000][8]
#define WS_HX_OFF      8192
#define WS_HY_OFF      12288
#define WS_HZ_OFF      16384
#define WS_S1_OFF      20480
#define WS_X_OFF       28672
#define WS_TABLE_BYTES 28672
#define WS_TIER2_BYTES 124672

__global__ __launch_bounds__(256) void k_init(const float* __restrict__ fc1_b,
                                              float* __restrict__ out) {
    int idx = blockIdx.x * 256 + threadIdx.x;
    out[idx] = fc1_b[idx & (HIDDEN - 1)];
}

// Table build: one WAVE per row (lane-parallel 64-dot + shuffle reduce).
// 512 blocks x 4 waves cover 2048 rows (pad rows write zeros via e=0).
// Replaces the old 8-block serial-per-thread version (~3 us -> <1 us).
__global__ __launch_bounds__(256) void k_prep(const float* __restrict__ emb,
                                              const float* __restrict__ W,
                                              const float* __restrict__ a,
                                              float* __restrict__ ws) {
    __shared__ float sW[GAT_EMB * 3];
    __shared__ float sa[6];
    int t = threadIdx.x;
    if (t < GAT_EMB * 3) sW[t] = W[t];
    if (t < 6)           sa[t] = a[t];
    __syncthreads();
    int lane = t & 63, w = t >> 6;
    int row = blockIdx.x * 4 + w;           // 0..2047
    float e = (row < N_ENT) ? emb[(size_t)row * GAT_EMB + lane] : 0.f;
    float p0 = e * sW[lane * 3 + 0];
    float p1 = e * sW[lane * 3 + 1];
    float p2 = e * sW[lane * 3 + 2];
#pragma unroll
    for (int off = 32; off > 0; off >>= 1) {
        p0 += __shfl_xor(p0, off, 64);
        p1 += __shfl_xor(p1, off, 64);
        p2 += __shfl_xor(p2, off, 64);
    }
    if (lane == 0) {
        ws[row] = p0 * sa[3] + p1 * sa[4] + p2 * sa[5];                 // s2
        ((_Float16*)((char*)ws + WS_HX_OFF))[row] = (_Float16)p0;
        ((_Float16*)((char*)ws + WS_HY_OFF))[row] = (_Float16)p1;
        ((_Float16*)((char*)ws + WS_HZ_OFF))[row] = (_Float16)p2;
        ws[WS_S1_OFF / 4 + row] = p0 * sa[0] + p1 * sa[1] + p2 * sa[2]; // s1
    }
}

// 1000 blocks x 512 threads; block = 16 contiguous rows of one batch b.
// Wave w: rows i_base+2w, +2w+1 (2 NT streams), 4-slot / issue-3-ahead
// register prefetch. launch_bounds(512,4) -> <=128 VGPRs: the old (256,4)
// build sat exactly at the 64-VGPR cap, which forces the compiler to shorten
// the prefetch pipeline (tight vmcnt) and collapses MLP -- the suspected
// cause of 494 GB/s effective streaming on a 6.9 TB/s-capable path.
// 16 rows/block also halves the 20 KB phase-1 table traffic per adj byte.
__global__ __launch_bounds__(512, 4) void k_main(const float* __restrict__ emb,
                                                 const float* __restrict__ W,
                                                 const float* __restrict__ a,
                                                 const float* __restrict__ fc1_w,
                                                 const int*   __restrict__ adj,
                                                 float* __restrict__ wsf,
                                                 int mode,
                                                 float* __restrict__ out) {
    __shared__ __align__(16) unsigned char smem[20480];
    float*    s2s = (float*)smem;
    _Float16* hxs = (_Float16*)(smem + 8192);
    _Float16* hys = (_Float16*)(smem + 12288);
    _Float16* hzs = (_Float16*)(smem + 16384);
    __shared__ float sW[GAT_EMB * 3];
    __shared__ float sa[6];
    __shared__ float s1sh[16];
    __shared__ float xblk[48];

    int t = threadIdx.x;
    int bid = blockIdx.x;
    int b  = bid / 125;                 // 125 blocks per batch, 16 rows each
    int i_base = (bid - b * 125) * 16;  // 16 | 2000 -> no batch straddle
    int R0 = b * N_ENT + i_base;

    if (mode != 0) {
        const uint4* src = (const uint4*)wsf;
        uint4* dst = (uint4*)smem;
        // 20480 B = 1280 uint4 over 512 threads
        dst[t]        = src[t];
        dst[512 + t]  = src[512 + t];
        if (t < 256) dst[1024 + t] = src[1024 + t];
        if (t < 16) s1sh[t] = wsf[WS_S1_OFF / 4 + i_base + t];
    } else {
        if (t < GAT_EMB * 3) sW[t] = W[t];
        if (t < 6)           sa[t] = a[t];
        __syncthreads();
        for (int j = t; j < N_ENT; j += 512) {
            const float4* er = (const float4*)(emb + (size_t)j * GAT_EMB);
            float h0 = 0.f, h1 = 0.f, h2 = 0.f;
#pragma unroll
            for (int k4 = 0; k4 < GAT_EMB / 4; ++k4) {
                float4 e4 = er[k4];
                int k = 4 * k4;
                h0 += e4.x * sW[(k + 0) * 3 + 0]; h1 += e4.x * sW[(k + 0) * 3 + 1]; h2 += e4.x * sW[(k + 0) * 3 + 2];
                h0 += e4.y * sW[(k + 1) * 3 + 0]; h1 += e4.y * sW[(k + 1) * 3 + 1]; h2 += e4.y * sW[(k + 1) * 3 + 2];
                h0 += e4.z * sW[(k + 2) * 3 + 0]; h1 += e4.z * sW[(k + 2) * 3 + 1]; h2 += e4.z * sW[(k + 2) * 3 + 2];
                h0 += e4.w * sW[(k + 3) * 3 + 0]; h1 += e4.w * sW[(k + 3) * 3 + 1]; h2 += e4.w * sW[(k + 3) * 3 + 2];
            }
            s2s[j] = h0 * sa[3] + h1 * sa[4] + h2 * sa[5];
            hxs[j] = (_Float16)h0; hys[j] = (_Float16)h1; hzs[j] = (_Float16)h2;
            if (j >= i_base && j < i_base + 16)
                s1sh[j - i_base] = h0 * sa[0] + h1 * sa[1] + h2 * sa[2];
        }
        if (t < 2048 - N_ENT) {
            int j = N_ENT + t;
            s2s[j] = 0.f; hxs[j] = (_Float16)0; hys[j] = (_Float16)0; hzs[j] = (_Float16)0;
        }
    }
    __syncthreads();

    // ---- Phase 2: 2 rows/wave, 8 chunks, issue-3-ahead NT prefetch ----
    int lane = t & 63;
    int w    = t >> 6;                  // 0..7
    float s1r[2];
    const int* __restrict__ rowp[2];
#pragma unroll
    for (int r = 0; r < 2; ++r) {
        s1r[r] = s1sh[2 * w + r];
        rowp[r] = adj + ((size_t)b * N_ENT + (i_base + 2 * w + r)) * N_ENT;
    }

    float acc[2][4];
#pragma unroll
    for (int r = 0; r < 2; ++r) { acc[r][0] = 0.f; acc[r][1] = 0.f; acc[r][2] = 0.f; acc[r][3] = 0.f; }

    int l4 = lane << 2;
    iv4 buf[4][2];
#pragma unroll
    for (int c = 0; c < 3; ++c)         // chunks 0..2: j <= 764, no clamp needed
#pragma unroll
        for (int r = 0; r < 2; ++r) buf[c][r] = nt_load4i(rowp[r] + c * 256 + l4);

#pragma unroll
    for (int c = 0; c < 8; ++c) {
        if (c + 3 < 8) {
            int j2 = (c + 3) * 256 + l4;
            int jc2 = (j2 < N_ENT) ? j2 : 0;        // only chunk 7 can clamp
#pragma unroll
            for (int r = 0; r < 2; ++r)
                buf[(c + 3) & 3][r] = nt_load4i(rowp[r] + jc2);
        }
        int j0 = c * 256 + l4;                      // <= 2044; LDS pad zeroed
        bool valid = (j0 < N_ENT);
        float vw = valid ? 1.0f : 0.0f;
        float4 s2v = *(const float4*)&s2s[j0];
        half4  hxv = *(const half4*)&hxs[j0];
        half4  hyv = *(const half4*)&hys[j0];
        half4  hzv = *(const half4*)&hzs[j0];
        float hx[4], hy[4], hz[4];
#pragma unroll
        for (int q = 0; q < 4; ++q) { hx[q] = (float)hxv[q]; hy[q] = (float)hyv[q]; hz[q] = (float)hzv[q]; }
#pragma unroll
        for (int r = 0; r < 2; ++r) {
            iv4 mv = buf[c & 3][r];
#pragma unroll
            for (int q = 0; q < 4; ++q) {
                float e  = s1r[r] + ((const float*)&s2v)[q];
                float ev = __expf(fmaxf(e, 0.f) + ALPHA * fminf(e, 0.f));
                float contrib = ((mv[q] > 0) ? ev : 1.0f) * vw;   // expf(9e-15)==1.0f exactly
                acc[r][0] += contrib;
                acc[r][1] += contrib * hx[q];
                acc[r][2] += contrib * hy[q];
                acc[r][3] += contrib * hz[q];
            }
        }
    }

#pragma unroll
    for (int off = 32; off > 0; off >>= 1)
#pragma unroll
        for (int r = 0; r < 2; ++r) {
            acc[r][0] += __shfl_xor(acc[r][0], off, 64);
            acc[r][1] += __shfl_xor(acc[r][1], off, 64);
            acc[r][2] += __shfl_xor(acc[r][2], off, 64);
            acc[r][3] += __shfl_xor(acc[r][3], off, 64);
        }

    if (lane == 0) {
#pragma unroll
        for (int r = 0; r < 2; ++r) {
            float inv = 1.f / acc[r][0];
            float p0 = acc[r][1] * inv, p1 = acc[r][2] * inv, p2 = acc[r][3] * inv;
            p0 = (p0 > 0.f) ? p0 : expm1f(p0);   // ELU
            p1 = (p1 > 0.f) ? p1 : expm1f(p1);
            p2 = (p2 > 0.f) ? p2 : expm1f(p2);
            if (mode == 2) {
                _Float16* x16 = (_Float16*)((char*)wsf + WS_X_OFF);
                int i = i_base + 2 * w + r;
                x16[(size_t)(3 * i + 0) * 8 + b] = (_Float16)p0;
                x16[(size_t)(3 * i + 1) * 8 + b] = (_Float16)p1;
                x16[(size_t)(3 * i + 2) * 8 + b] = (_Float16)p2;
            } else {
                int cc = 3 * (2 * w + r);
                xblk[cc + 0] = p0; xblk[cc + 1] = p1; xblk[cc + 2] = p2;
            }
        }
    }

    if (mode != 2) {   // fallback: atomic FC for this block's 48 columns, one batch b
        __syncthreads();
        if (t < 256) {
            int k = (t + R0) & 255;
            const float* wr = fc1_w + (size_t)k * (N_ENT * 3) + 3 * i_base;  // 48 floats, 8B-aligned
            float d = 0.f;
#pragma unroll
            for (int c2 = 0; c2 < 24; ++c2) {
                float2 wv = *(const float2*)(wr + 2 * c2);
                d += xblk[2 * c2 + 0] * wv.x + xblk[2 * c2 + 1] * wv.y;
            }
            atomicAdd(&out[b * HIDDEN + k], d);
        }
    }
}

// out[b,k] = fc1_b[k] + sum_m x16[m][b] * fc1_w[k][m]; 256 blocks (one per k).
// fc1_w via NT loads (6 MB through poison-dirtied caches).
__global__ __launch_bounds__(256) void k_fc(const _Float16* __restrict__ x16,
                                            const float* __restrict__ fc1_w,
                                            const float* __restrict__ fc1_b,
                                            float* __restrict__ out) {
    __shared__ float red[4][8];
    int t = threadIdx.x, lane = t & 63, w = t >> 6;
    int k = blockIdx.x;
    const float* __restrict__ wr = fc1_w + (size_t)k * (N_ENT * 3);
    float acc[BATCH];
#pragma unroll
    for (int b = 0; b < BATCH; ++b) acc[b] = 0.f;
#pragma unroll
    for (int it = 0; it < 6; ++it) {
        int m0 = 4 * t + 1024 * it;
        if (m0 + 3 < N_ENT * 3) {
            fv4 wv4 = nt_load4f(wr + m0);
#pragma unroll
            for (int q = 0; q < 4; ++q) {
                half4 xa = *(const half4*)(x16 + (size_t)(m0 + q) * 8);
                half4 xb = *(const half4*)(x16 + (size_t)(m0 + q) * 8 + 4);
                float wv = wv4[q];
                acc[0] += wv * (float)xa[0]; acc[1] += wv * (float)xa[1];
                acc[2] += wv * (float)xa[2]; acc[3] += wv * (float)xa[3];
                acc[4] += wv * (float)xb[0]; acc[5] += wv * (float)xb[1];
                acc[6] += wv * (float)xb[2]; acc[7] += wv * (float)xb[3];
            }
        }
    }
#pragma unroll
    for (int off = 32; off > 0; off >>= 1)
#pragma unroll
        for (int b = 0; b < BATCH; ++b) acc[b] += __shfl_xor(acc[b], off, 64);
    if (lane == 0)
#pragma unroll
        for (int b = 0; b < BATCH; ++b) red[w][b] = acc[b];
    __syncthreads();
    if (t < 8)
        out[t * HIDDEN + k] = red[0][t] + red[1][t] + red[2][t] + red[3][t] + fc1_b[k];
}

extern "C" void kernel_launch(void* const* d_in, const int* in_sizes, int n_in,
                              void* d_out, int out_size, void* d_ws, size_t ws_size,
                              hipStream_t stream) {
    const float* emb   = (const float*)d_in[0];
    const float* W     = (const float*)d_in[1];
    const float* a     = (const float*)d_in[2];
    const float* fc1_w = (const float*)d_in[3];
    const float* fc1_b = (const float*)d_in[4];
    const int*   adj   = (const int*)d_in[5];
    float* out = (float*)d_out;
    float* ws  = (float*)d_ws;
    (void)in_sizes; (void)n_in; (void)out_size;

    int tier = (ws_size >= (size_t)WS_TIER2_BYTES) ? 2
             : (ws_size >= (size_t)WS_TABLE_BYTES) ? 1 : 0;

    if (tier < 2)  k_init<<<8, 256, 0, stream>>>(fc1_b, out);
    if (tier >= 1) k_prep<<<512, 256, 0, stream>>>(emb, W, a, ws);
    k_main<<<1000, 512, 0, stream>>>(emb, W, a, fc1_w, adj, ws, tier, out);
    if (tier == 2)
        k_fc<<<HIDDEN, 256, 0, stream>>>((const _Float16*)((char*)d_ws + WS_X_OFF),
                                         fc1_w, fc1_b, out);
}